// Round 7
// baseline (383.942 us; speedup 1.0000x reference)
//
#include <hip/hip_runtime.h>
#include <math.h>

#define B_ 4
#define K_ 4096
#define C_ 256
#define H_ 128
#define RAD 5
#define NB (2 * RAD + 1)
#define PSTRIDE 12     // 11 band weights + woff
#define TROWS 16       // rows per store block

typedef float floatx4 __attribute__((ext_vector_type(4)));

// ws layout (floats):
//   s:       [B_*K_]          @ 0
//   Ssum:    [B_*C_]          @ 16384
//   partial: [512*C_]         @ 17408
//   params:  [B_*K_*PSTRIDE]  @ 148480

// ---------------- K1: per-token MLP score ----------------
__global__ __launch_bounds__(128) void score_kernel(
    const float* __restrict__ x, const float* __restrict__ W1,
    const float* __restrict__ b1, const float* __restrict__ W2,
    const float* __restrict__ b2, float* __restrict__ s_out)
{
    const int tid = threadIdx.x;
    const int t0 = blockIdx.x * 8;
    const float* xr[8];
    #pragma unroll
    for (int t = 0; t < 8; ++t) xr[t] = x + (size_t)(t0 + t) * C_;

    float acc[8];
    float binit = b1[tid];
    #pragma unroll
    for (int t = 0; t < 8; ++t) acc[t] = binit;

    for (int c = 0; c < C_; c += 4) {
        float w0 = W1[(c + 0) * H_ + tid];
        float w1 = W1[(c + 1) * H_ + tid];
        float w2 = W1[(c + 2) * H_ + tid];
        float w3 = W1[(c + 3) * H_ + tid];
        #pragma unroll
        for (int t = 0; t < 8; ++t) {
            floatx4 xv = *(const floatx4*)&xr[t][c];   // wave-uniform -> s_load
            acc[t] = fmaf(xv.x, w0, acc[t]);
            acc[t] = fmaf(xv.y, w1, acc[t]);
            acc[t] = fmaf(xv.z, w2, acc[t]);
            acc[t] = fmaf(xv.w, w3, acc[t]);
        }
    }

    __shared__ float red[2][8];
    float w2v = W2[tid];
    #pragma unroll
    for (int t = 0; t < 8; ++t) {
        float p = tanhf(acc[t]) * w2v;
        #pragma unroll
        for (int off = 32; off > 0; off >>= 1) p += __shfl_down(p, off);
        if ((tid & 63) == 0) red[tid >> 6][t] = p;
    }
    __syncthreads();
    if (tid < 8) s_out[t0 + tid] = red[0][tid] + red[1][tid] + b2[0];
}

// ---------------- K2a/K2b: per-batch column sums ----------------
__global__ __launch_bounds__(256) void colsum_partial(
    const float* __restrict__ x, float* __restrict__ partial)
{
    const int tid = threadIdx.x;
    const int blk = blockIdx.x;
    const float* base = x + (size_t)blk * 32 * C_ + tid;
    float a0 = 0.f, a1 = 0.f, a2 = 0.f, a3 = 0.f;
    #pragma unroll
    for (int kk = 0; kk < 32; kk += 4) {
        a0 += base[(size_t)(kk + 0) * C_];
        a1 += base[(size_t)(kk + 1) * C_];
        a2 += base[(size_t)(kk + 2) * C_];
        a3 += base[(size_t)(kk + 3) * C_];
    }
    partial[(size_t)blk * C_ + tid] = (a0 + a1) + (a2 + a3);
}

// 1024 threads: (channel c = tid&255, group g = tid>>8); g sums 32 chunks.
__global__ __launch_bounds__(1024) void colsum_final(
    const float* __restrict__ partial, float* __restrict__ Ssum)
{
    const int c = threadIdx.x & 255;
    const int g = threadIdx.x >> 8;
    const int b = blockIdx.x;
    __shared__ float red[4][C_];
    float acc = 0.f;
    const float* pb = partial + ((size_t)b * 128 + g * 32) * C_ + c;
    #pragma unroll 4
    for (int ch = 0; ch < 32; ++ch) acc += pb[(size_t)ch * C_];
    red[g][c] = acc;
    __syncthreads();
    if (g == 0) Ssum[b * C_ + c] = red[0][c] + red[1][c] + red[2][c] + red[3][c];
}

// ---------------- K3: softmax params, one THREAD per row ----------------
__global__ __launch_bounds__(256) void params_kernel(
    const float* __restrict__ s, float* __restrict__ params)
{
    const int row = blockIdx.x * 256 + threadIdx.x;   // b*K_ + i
    const int b = row >> 12;
    const int i = row & (K_ - 1);
    const int j0 = max(0, i - RAD), j1 = min(K_ - 1, i + RAD);
    const int nb = j1 - j0 + 1;
    const float* srow = s + b * K_;

    float sv[NB];
    float m = 0.f;                                    // off-band score 0 => max >= 0
    #pragma unroll
    for (int jj = 0; jj < NB; ++jj) {
        float v = (jj < nb) ? srow[j0 + jj] : 0.f;
        sv[jj] = v;
        if (jj < nb) m = fmaxf(m, v);
    }
    float e0 = expf(-m);
    float D = (float)(K_ - nb) * e0;
    float* pp = params + (size_t)row * PSTRIDE;
    #pragma unroll
    for (int jj = 0; jj < NB; ++jj) {
        float e = expf(sv[jj] - m);
        if (jj < nb) D += e;
        sv[jj] = e;
    }
    float inv = 1.0f / D;
    #pragma unroll
    for (int jj = 0; jj < NB; ++jj) pp[jj] = sv[jj] * inv;  // jj>=nb slots unread
    pp[11] = e0 * inv;
}

// ---------------- K4: streaming store kernel, 16 rows per block ----------------
// 1024 blocks (4/CU, fully co-resident). Stage params + x band in LDS once,
// then stream 272 KB of plain stores per block (matches fill kernel's path).
__global__ __launch_bounds__(256) void store16_kernel(
    const float* __restrict__ x, const float* __restrict__ params,
    const float* __restrict__ Ssum, float* __restrict__ out)
{
    const int tid = threadIdx.x;
    const int blk = blockIdx.x;                       // b*(K_/TROWS) + tile
    const int b  = blk >> 8;                          // K_/TROWS = 256
    const int i0 = (blk & 255) * TROWS;

    const int j0t = max(0, i0 - RAD);
    const int j1t = min(K_ - 1, i0 + TROWS - 1 + RAD);
    const int ntok = j1t - j0t + 1;                   // <= 26

    __shared__ float xs[TROWS + 2 * RAD][C_];         // 26 KB
    __shared__ float prm[TROWS][PSTRIDE];             // 768 B

    if (tid < TROWS * PSTRIDE)
        ((float*)prm)[tid] = params[(size_t)(b * K_ + i0) * PSTRIDE + tid];
    const floatx4* xsrc = (const floatx4*)(x + ((size_t)b * K_ + j0t) * C_);
    floatx4* xdst = (floatx4*)&xs[0][0];
    for (int f = tid; f < ntok * (C_ / 4); f += 256) xdst[f] = xsrc[f];
    __syncthreads();

    // ---- weighted rows: thread owns channel tid ----
    const float sc = Ssum[b * C_ + tid];
    #pragma unroll
    for (int r = 0; r < TROWS; ++r) {
        const int i = i0 + r;
        const int j0 = max(0, i - RAD), j1 = min(K_ - 1, i + RAD);
        const float wo = prm[r][11];
        float acc = wo * sc;
        for (int j = j0; j <= j1; ++j)
            acc = fmaf(prm[r][j - j0] - wo, xs[j - j0t][tid], acc);
        out[((size_t)b * K_ + i) * C_ + tid] = acc;
    }

    // ---- weights rows: 16 x 16 KB contiguous streams ----
    float* wbase = out + (size_t)B_ * K_ * C_ + ((size_t)b * K_ + i0) * K_;
    #pragma unroll
    for (int r = 0; r < TROWS; ++r) {
        const int i = i0 + r;
        const int j0 = max(0, i - RAD), j1 = min(K_ - 1, i + RAD);
        const float wo = prm[r][11];
        floatx4* wrow4 = (floatx4*)(wbase + (size_t)r * K_);
        #pragma unroll
        for (int q = 0; q < 4; ++q) {
            const int f = tid + 256 * q;
            const int jb = f * 4;
            floatx4 v = { wo, wo, wo, wo };
            if (jb + 3 >= j0 && jb <= j1) {           // rare: band overlap
                if (jb + 0 >= j0 && jb + 0 <= j1) v.x = prm[r][jb + 0 - j0];
                if (jb + 1 >= j0 && jb + 1 <= j1) v.y = prm[r][jb + 1 - j0];
                if (jb + 2 >= j0 && jb + 2 <= j1) v.z = prm[r][jb + 2 - j0];
                if (jb + 3 >= j0 && jb + 3 <= j1) v.w = prm[r][jb + 3 - j0];
            }
            wrow4[f] = v;
        }
    }
}

extern "C" void kernel_launch(void* const* d_in, const int* in_sizes, int n_in,
                              void* d_out, int out_size, void* d_ws, size_t ws_size,
                              hipStream_t stream) {
    const float* x  = (const float*)d_in[0];
    const float* W1 = (const float*)d_in[1];
    const float* b1 = (const float*)d_in[2];
    const float* W2 = (const float*)d_in[3];
    const float* b2 = (const float*)d_in[4];
    float* out = (float*)d_out;

    float* ws      = (float*)d_ws;
    float* s       = ws;                      // 16384
    float* Ssum    = ws + 16384;              // 1024
    float* partial = ws + 17408;              // 131072
    float* params  = ws + 148480;             // 196608

    score_kernel  <<<B_ * K_ / 8,      128,  0, stream>>>(x, W1, b1, W2, b2, s);
    colsum_partial<<<B_ * 128,         256,  0, stream>>>(x, partial);
    colsum_final  <<<B_,               1024, 0, stream>>>(partial, Ssum);
    params_kernel <<<B_ * K_ / 256,    256,  0, stream>>>(s, params);
    store16_kernel<<<B_ * K_ / TROWS,  256,  0, stream>>>(x, params, Ssum, out);
}